// Round 15
// baseline (47.056 us; speedup 1.0000x reference)
//
#include <hip/hip_runtime.h>

#define NB    128           // DTW block size N
#define NCH   64            // channels
#define RSTR  132           // u8 D row stride (pad 4 -> bank spread + window slack)
#define BOFF  16896         // bnd float array starts here (128*132); 260*4 B
#define DKQ   2.8853900817779268f   // 2*log2e: u8 decode folded into D-term FMA
#define LN2   0.6931471805599453f
#define LOG2E 1.4426950408889634f
#define LARGE 1e9f

typedef _Float16 h16;
typedef __attribute__((ext_vector_type(8))) _Float16 h16x8;
typedef __attribute__((ext_vector_type(4))) float    f32x4;

static __device__ __forceinline__ float ex2(float x) {
#if __has_builtin(__builtin_amdgcn_exp2f)
    return __builtin_amdgcn_exp2f(x);
#else
    return exp2f(x);
#endif
}

static __device__ __forceinline__ float lg2(float x) {
#if __has_builtin(__builtin_amdgcn_logf)
    return __builtin_amdgcn_logf(x);   // v_log_f32 = log2
#else
    return log2f(x);
#endif
}

// lane t gets lane t-1's src; lane 0 gets `fill`. Pure VALU (DPP wave_shr:1).
static __device__ __forceinline__ float shift_up1(float src, float fill) {
    int r = __builtin_amdgcn_update_dpp(__builtin_bit_cast(int, fill),
                                        __builtin_bit_cast(int, src),
                                        0x138 /*wave_shr:1*/, 0xf, 0xf, false);
    return __builtin_bit_cast(float, r);
}

// soft-min of 3 in log2 domain + Dq*(2*log2e); Dq = raw u8 byte (D/2).
// Exact trans form (r10 showed PWL/issue-heavy forms are slower).
static __device__ __forceinline__ float softmin3q(float a, float b, float c, float Dq) {
    float m = fminf(fminf(a, b), c);
    float M = fmaxf(fmaxf(a, b), c);
#if __has_builtin(__builtin_amdgcn_fmed3f)
    float e = __builtin_amdgcn_fmed3f(a, b, c);
#else
    float e = ((a + b) + c) - m - M;
#endif
    float s = 1.0f + (ex2(m - e) + ex2(m - M));
    return fmaf(Dq, DKQ, m - lg2(s));
}

__global__ __launch_bounds__(128, 1)
void dtw_k(const float* __restrict__ X, const float* __restrict__ Y,
           float* __restrict__ out, int nbpb)
{
    __shared__ unsigned char sLDS[BOFF + 260 * 4];   // D (u8, 128x132) + bnd f32[260]

    const int w   = blockIdx.x;            // block-pair id
    const int tid = threadIdx.x;           // 0..127
    const int wid = tid >> 6;              // 0 = wave A (rows 0-63), 1 = wave B (64-127)
    const int t   = tid & 63;              // lane
    const int c = t & 15, g = t >> 4;      // MFMA fragment coords
    char* sDb = (char*)sLDS;
    float* bndA = (float*)(sDb + BOFF);    // bndA[0..259]
    float* bnd  = bndA + 2;                // bnd[-2..257] valid; bnd[s] = R~[63][s-63]
    const float* gx = X + (size_t)w * (NB * NCH);
    const float* gy = Y + (size_t)w * (NB * NCH);

    // ---- bnd init (both waves): LARGE everywhere (junk/pre-valid reads safe)
    for (int i = tid; i < 260; i += 128) bndA[i] = LARGE;

    // ---- build: each wave builds its own 64 D rows (4 tiles of 16).
    // B fragments (full y) + y2 norms per wave, in registers (r7-verified math).
    {
        h16x8 Bf[8][2];
        float y2r[8];
        #pragma unroll
        for (int J = 0; J < 8; ++J) {
            const float* py = gy + (16 * J + c) * NCH + 8 * g;
            float p = 0.f;
            #pragma unroll
            for (int q = 0; q < 2; ++q) {
                float4 a = *(const float4*)(py + 32 * q);
                float4 b = *(const float4*)(py + 32 * q + 4);
                h16x8 h;
                h[0]=(h16)a.x; h[1]=(h16)a.y; h[2]=(h16)a.z; h[3]=(h16)a.w;
                h[4]=(h16)b.x; h[5]=(h16)b.y; h[6]=(h16)b.z; h[7]=(h16)b.w;
                Bf[J][q] = h;
                p = fmaf(a.x,a.x,p); p = fmaf(a.y,a.y,p);
                p = fmaf(a.z,a.z,p); p = fmaf(a.w,a.w,p);
                p = fmaf(b.x,b.x,p); p = fmaf(b.y,b.y,p);
                p = fmaf(b.z,b.z,p); p = fmaf(b.w,b.w,p);
            }
            p += __shfl_xor(p, 16, 64);
            p += __shfl_xor(p, 32, 64);
            y2r[J] = p;                      // ||y[16J+c]||^2
        }

        const int RB = wid * 64;            // this wave's row base
        float4 nx0, nx1, nx2, nx3;
        {
            const float* px = gx + (RB + c) * NCH + 8 * g;
            nx0 = *(const float4*)(px);      nx1 = *(const float4*)(px + 4);
            nx2 = *(const float4*)(px + 32); nx3 = *(const float4*)(px + 36);
        }
        for (int I = 0; I < 4; ++I) {
            float4 a0 = nx0, a1 = nx1, a2 = nx2, a3 = nx3;
            if (I < 3) {
                const float* px = gx + (RB + 16 * (I + 1) + c) * NCH + 8 * g;
                nx0 = *(const float4*)(px);      nx1 = *(const float4*)(px + 4);
                nx2 = *(const float4*)(px + 32); nx3 = *(const float4*)(px + 36);
            }
            h16x8 Af0, Af1;
            Af0[0]=(h16)a0.x; Af0[1]=(h16)a0.y; Af0[2]=(h16)a0.z; Af0[3]=(h16)a0.w;
            Af0[4]=(h16)a1.x; Af0[5]=(h16)a1.y; Af0[6]=(h16)a1.z; Af0[7]=(h16)a1.w;
            Af1[0]=(h16)a2.x; Af1[1]=(h16)a2.y; Af1[2]=(h16)a2.z; Af1[3]=(h16)a2.w;
            Af1[4]=(h16)a3.x; Af1[5]=(h16)a3.y; Af1[6]=(h16)a3.z; Af1[7]=(h16)a3.w;
            float p = 0.f;
            p=fmaf(a0.x,a0.x,p); p=fmaf(a0.y,a0.y,p); p=fmaf(a0.z,a0.z,p); p=fmaf(a0.w,a0.w,p);
            p=fmaf(a1.x,a1.x,p); p=fmaf(a1.y,a1.y,p); p=fmaf(a1.z,a1.z,p); p=fmaf(a1.w,a1.w,p);
            p=fmaf(a2.x,a2.x,p); p=fmaf(a2.y,a2.y,p); p=fmaf(a2.z,a2.z,p); p=fmaf(a2.w,a2.w,p);
            p=fmaf(a3.x,a3.x,p); p=fmaf(a3.y,a3.y,p); p=fmaf(a3.z,a3.z,p); p=fmaf(a3.w,a3.w,p);
            p += __shfl_xor(p, 16, 64);
            p += __shfl_xor(p, 32, 64);
            float xa[4];
            xa[0] = __shfl(p, 4 * g + 0, 64);
            xa[1] = __shfl(p, 4 * g + 1, 64);
            xa[2] = __shfl(p, 4 * g + 2, 64);
            xa[3] = __shfl(p, 4 * g + 3, 64);

            f32x4 acc[8];
            #pragma unroll
            for (int J = 0; J < 8; ++J) {
                f32x4 z = {0.f, 0.f, 0.f, 0.f};
                z = __builtin_amdgcn_mfma_f32_16x16x32_f16(Af0, Bf[J][0], z, 0, 0, 0);
                z = __builtin_amdgcn_mfma_f32_16x16x32_f16(Af1, Bf[J][1], z, 0, 0, 0);
                acc[J] = z;
            }
            #pragma unroll
            for (int J = 0; J < 8; ++J) {
                char* base = sDb + (16 * J + c) + RSTR * (RB + 16 * I + 4 * g);
                float y2v = y2r[J];
                #pragma unroll
                for (int r = 0; r < 4; ++r) {
                    float dv = fmaf(-2.0f, acc[J][r], xa[r] + y2v);
                    unsigned u = (unsigned)fmaf(dv, 0.5f, 0.5f);
                    u = u > 255u ? 255u : u;
                    *(unsigned char*)(base + RSTR * r) = (unsigned char)u;
                }
            }
        }
    }
    __syncthreads();                        // D + bnd init complete

    // ---- pipelined dual-wave DP. 1 row/lane: state = {r1, dgp}.
    // Wave A: rows 0-63, chunk p in phase p. Wave B: rows 64-127, chunk p-1 in
    // phase p (reads A's boundary, published one chunk earlier). 17 phases.
    const unsigned char* sDu = (const unsigned char*)sDb;
    float r1  = LARGE;
    float dgp = (wid == 0 && t == 0) ? 0.0f : LARGE;   // corner R[-1][-1]=0

    for (int p = 0; p < 17; ++p) {
        if (wid == 0) {
            if (p < 16) {
                const int cbase = 131 * t + 16 * p;     // row t, col 16p+k-t
                float fD[16];
                #pragma unroll
                for (int k = 0; k < 16; ++k) fD[k] = (float)sDu[cbase + k];
                float bb[16];
                #pragma unroll
                for (int k = 0; k < 16; ++k) {
                    float up = shift_up1(r1, LARGE);
                    float n  = softmin3q(r1, up, dgp, fD[k]);
                    dgp = up; r1 = n; bb[k] = n;
                }
                if (t == 63) {                          // publish R~[63][16p+k-63]
                    float* bw = bnd + 16 * p;
                    #pragma unroll
                    for (int k = 0; k < 16; ++k) bw[k] = bb[k];
                }
            }
        } else {
            if (p >= 1) {
                const int q = p - 1;
                const int cbase = 8384 + 131 * t + 16 * q;  // row 64+t
                float fD[16];
                #pragma unroll
                for (int k = 0; k < 16; ++k) fD[k] = (float)sDu[cbase + k];
                float bv[16];                           // bnd[16q-1+k] = up for lane 0
                #pragma unroll
                for (int k = 0; k < 16; ++k) bv[k] = bnd[16 * q - 1 + k];
                const int kmax = (q == 15) ? 15 : 16;   // stop at d=254
                #pragma unroll
                for (int k = 0; k < 16; ++k) {
                    if (k < kmax) {
                        float up = shift_up1(r1, LARGE);
                        up = (t == 0) ? bv[k] : up;     // row-64 up from boundary
                        float n  = softmin3q(r1, up, dgp, fD[k]);
                        dgp = up; r1 = n;               // lane0 diag = prev bnd (carried)
                    }
                }
            }
        }
        __syncthreads();
    }

    if (tid == 127) {                       // wave B lane 63: R~[127][127]
        atomicAdd(&out[w / nbpb], r1 * LN2);
    }
}

extern "C" void kernel_launch(void* const* d_in, const int* in_sizes, int n_in,
                              void* d_out, int out_size, void* d_ws, size_t ws_size,
                              hipStream_t stream) {
    const float* x = (const float*)d_in[0];
    const float* y = (const float*)d_in[1];
    float* out = (float*)d_out;

    const int nblk = in_sizes[0] / (NB * NCH);   // 1024 block-pairs
    const int nbpb = nblk / out_size;            // 32 blocks per batch

    hipMemsetAsync(out, 0, (size_t)out_size * sizeof(float), stream);
    dtw_k<<<nblk, 128, 0, stream>>>(x, y, out, nbpb);
}